// Round 1
// baseline (14083.002 us; speedup 1.0000x reference)
//
#include <hip/hip_runtime.h>
#include <math.h>

#define MF 9
#define CTX 5
#define HID 128
#define LPE 8
#define LNUM 3

__device__ __forceinline__ float silu_f(float v) { return v / (1.0f + __expf(-v)); }

// ---------------- node init: x = wte[pos_w] + pos @ node_W^T + node_b ----------------
__global__ void k_node_init(const float* __restrict__ pos, const int* __restrict__ pos_w,
                            const float* __restrict__ wte, const float* __restrict__ nW,
                            const float* __restrict__ nb, float* __restrict__ x)
{
    int n = blockIdx.x;
    int t = threadIdx.x;
    __shared__ float sp[LPE];
    if (t < LPE) sp[t] = pos[(size_t)n * LPE + t];
    __syncthreads();
    float acc = nb[t];
    const float* w = nW + t * LPE;
#pragma unroll
    for (int j = 0; j < LPE; ++j) acc = fmaf(sp[j], w[j], acc);
    int pw = pos_w[n];
    x[(size_t)n * HID + t] = wte[(size_t)pw * HID + t] + acc;
}

// ---------------- edge init: e = layer_embed[type] + edge_attr @ edge_W^T + edge_b; res extract ----
__global__ __launch_bounds__(256)
void k_edge_init(const float* __restrict__ eattr, const int* __restrict__ etype,
                 const float* __restrict__ lemb, const float* __restrict__ eW,
                 const float* __restrict__ eb, float* __restrict__ e,
                 float* __restrict__ res)
{
    __shared__ float sW[HID][49];   // pad 45->49 to break bank conflicts
    __shared__ float sR[16][49];
    int tid = threadIdx.x;
    int e0 = blockIdx.x * 16;
    for (int li = tid; li < HID * 45; li += 256) { int c = li / 45, k = li % 45; sW[c][k] = eW[li]; }
    for (int li = tid; li < 16 * 45; li += 256) { int el = li / 45, k = li % 45; sR[el][k] = eattr[(size_t)(e0 + el) * 45 + k]; }
    __syncthreads();
    if (tid < 16 * MF) { int el = tid / MF, f = tid % MF; res[(size_t)(e0 + el) * MF + f] = sR[el][f * CTX + (CTX - 1)]; }
    int eg = tid >> 5, cg = tid & 31;
    int el0 = eg * 2, c0 = cg * 4;
    float acc[2][4] = {};
    for (int k = 0; k < 45; ++k) {
        float a0 = sR[el0][k], a1 = sR[el0 + 1][k];
#pragma unroll
        for (int j = 0; j < 4; ++j) {
            float w = sW[c0 + j][k];
            acc[0][j] = fmaf(a0, w, acc[0][j]);
            acc[1][j] = fmaf(a1, w, acc[1][j]);
        }
    }
    float4 b = ((const float4*)eb)[cg];
#pragma unroll
    for (int i = 0; i < 2; ++i) {
        int ge = e0 + el0 + i;
        int ty = etype[ge];
        float4 lv = ((const float4*)lemb)[ty * 32 + cg];
        float4 o;
        o.x = acc[i][0] + lv.x + b.x;
        o.y = acc[i][1] + lv.y + b.y;
        o.z = acc[i][2] + lv.z + b.z;
        o.w = acc[i][3] + lv.w + b.w;
        ((float4*)e)[(size_t)ge * 32 + cg] = o;
    }
}

// ---------------- degree count ----------------
__global__ void k_deg(const int* __restrict__ dst, float* __restrict__ deg, int E)
{
    int i = blockIdx.x * 256 + threadIdx.x;
    if (i < E) atomicAdd(&deg[dst[i]], 1.0f);
}

// ---------------- generic 16-row x 128-col tile GEMM, K = K4*4, A in LDS (float4, padded stride) ----
template <int K4>
__device__ __forceinline__ void gemm_tile(const float4* __restrict__ Wg, const float4* sA, int saStride,
                                          float4* Wbuf, int el0, int cg, float acc[2][4], int tid)
{
    for (int ch = 0; ch < K4 / 8; ++ch) {
#pragma unroll
        for (int r = 0; r < 4; ++r) {
            int li = r * 256 + tid;
            int kg = li >> 7, c = li & 127;
            Wbuf[kg * 128 + c] = Wg[(size_t)c * K4 + ch * 8 + kg];
        }
        __syncthreads();
#pragma unroll
        for (int kg = 0; kg < 8; ++kg) {
            float4 a0 = sA[(el0 + 0) * saStride + ch * 8 + kg];
            float4 a1 = sA[(el0 + 1) * saStride + ch * 8 + kg];
#pragma unroll
            for (int j = 0; j < 4; ++j) {
                float4 w = Wbuf[kg * 128 + cg * 4 + j];
                acc[0][j] = fmaf(a0.x, w.x, fmaf(a0.y, w.y, fmaf(a0.z, w.z, fmaf(a0.w, w.w, acc[0][j]))));
                acc[1][j] = fmaf(a1.x, w.x, fmaf(a1.y, w.y, fmaf(a1.z, w.z, fmaf(a1.w, w.w, acc[1][j]))));
            }
        }
        __syncthreads();
    }
}

// ---------------- per-layer fused: e' = silu([xs|xd|e]@We^T+be); m = silu([xs|xd|e']@Wpre^T+bpre);
//                  agg[dst] += m  (e updated in place; each edge owned by exactly one block) ----------
__global__ __launch_bounds__(256)
void k_edge_msg(const float* __restrict__ x, float* __restrict__ e,
                const int* __restrict__ src, const int* __restrict__ dst,
                const float* __restrict__ We, const float* __restrict__ be,
                const float* __restrict__ Wpre, const float* __restrict__ bpre,
                float* __restrict__ agg)
{
    __shared__ float4 sA[16 * 97];    // [16 rows][96 f4 = 384 f32], padded stride 97
    __shared__ float4 Wbuf[1024];     // 32k x 128c chunk
    __shared__ int sS[16], sD[16];
    int tid = threadIdx.x;
    int e0 = blockIdx.x * 16;
    if (tid < 16) sS[tid] = src[e0 + tid];
    else if (tid < 32) sD[tid - 16] = dst[e0 + tid - 16];
    __syncthreads();
    const float4* x4 = (const float4*)x;
    const float4* e4 = (const float4*)e;
#pragma unroll
    for (int r = 0; r < 6; ++r) {
        int li = r * 256 + tid;       // 16 edges * 96 f4
        int el = li / 96, k4 = li % 96;
        float4 v;
        if (k4 < 32) v = x4[(size_t)sS[el] * 32 + k4];
        else if (k4 < 64) v = x4[(size_t)sD[el] * 32 + (k4 - 32)];
        else v = e4[(size_t)(e0 + el) * 32 + (k4 - 64)];
        sA[el * 97 + k4] = v;
    }
    __syncthreads();
    int eg = tid >> 5, cg = tid & 31;
    int el0 = eg * 2;
    float acc[2][4] = {};
    gemm_tile<96>((const float4*)We, sA, 97, Wbuf, el0, cg, acc, tid);
    float4 b1 = ((const float4*)be)[cg];
    float4 enew[2];
#pragma unroll
    for (int i = 0; i < 2; ++i) {
        enew[i].x = silu_f(acc[i][0] + b1.x);
        enew[i].y = silu_f(acc[i][1] + b1.y);
        enew[i].z = silu_f(acc[i][2] + b1.z);
        enew[i].w = silu_f(acc[i][3] + b1.w);
    }
    // gemm_tile ends with __syncthreads(): all reads of old e are complete
#pragma unroll
    for (int i = 0; i < 2; ++i) {
        sA[(el0 + i) * 97 + 64 + cg] = enew[i];
        ((float4*)e)[(size_t)(e0 + el0 + i) * 32 + cg] = enew[i];
    }
    __syncthreads();
    float acc2[2][4] = {};
    gemm_tile<96>((const float4*)Wpre, sA, 97, Wbuf, el0, cg, acc2, tid);
    float4 b2v = ((const float4*)bpre)[cg];
#pragma unroll
    for (int i = 0; i < 2; ++i) {
        float* ap = agg + (size_t)sD[el0 + i] * HID + cg * 4;
        atomicAdd(ap + 0, silu_f(acc2[i][0] + b2v.x));
        atomicAdd(ap + 1, silu_f(acc2[i][1] + b2v.y));
        atomicAdd(ap + 2, silu_f(acc2[i][2] + b2v.z));
        atomicAdd(ap + 3, silu_f(acc2[i][3] + b2v.w));
    }
}

// ---------------- node update: x' = [x | agg/deg] @ Wpost^T + bpost (silu if not last) -------------
__global__ __launch_bounds__(256)
void k_x_upd(const float* __restrict__ x, const float* __restrict__ agg,
             const float* __restrict__ deg, const float* __restrict__ Wpost,
             const float* __restrict__ bpost, float* __restrict__ xout, int doSilu)
{
    __shared__ float4 sA[16 * 65];    // [16][64 f4 = 256 f32], stride 65
    __shared__ float4 Wbuf[1024];
    int tid = threadIdx.x;
    int n0 = blockIdx.x * 16;
    const float4* x4 = (const float4*)x;
    const float4* a4 = (const float4*)agg;
#pragma unroll
    for (int r = 0; r < 4; ++r) {
        int li = r * 256 + tid;
        int el = li >> 6, k4 = li & 63;
        int n = n0 + el;
        float4 v;
        if (k4 < 32) v = x4[(size_t)n * 32 + k4];
        else {
            float invd = 1.0f / fmaxf(deg[n], 1.0f);
            float4 a = a4[(size_t)n * 32 + (k4 - 32)];
            v = make_float4(a.x * invd, a.y * invd, a.z * invd, a.w * invd);
        }
        sA[el * 65 + k4] = v;
    }
    __syncthreads();
    int eg = tid >> 5, cg = tid & 31;
    int el0 = eg * 2;
    float acc[2][4] = {};
    gemm_tile<64>((const float4*)Wpost, sA, 65, Wbuf, el0, cg, acc, tid);
    float4 b = ((const float4*)bpost)[cg];
#pragma unroll
    for (int i = 0; i < 2; ++i) {
        float4 o;
        o.x = acc[i][0] + b.x; o.y = acc[i][1] + b.y; o.z = acc[i][2] + b.z; o.w = acc[i][3] + b.w;
        if (doSilu) { o.x = silu_f(o.x); o.y = silu_f(o.y); o.z = silu_f(o.z); o.w = silu_f(o.w); }
        ((float4*)xout)[(size_t)(n0 + el0 + i) * 32 + cg] = o;
    }
}

// ---------------- readout: h = silu(e@W1^T+b1); out = h@W2^T + b2 + res ----------------
__global__ __launch_bounds__(256)
void k_readout(const float* __restrict__ e, const float* __restrict__ W1,
               const float* __restrict__ b1, const float* __restrict__ W2,
               const float* __restrict__ b2, const float* __restrict__ res,
               float* __restrict__ out)
{
    __shared__ float4 smem[528 + 2880];   // 54.5 KB
    float4* sH = smem;                    // [16][33]
    float4* sE = smem + 528;              // [16][33] (dead after h-GEMM)
    float4* Wbuf = smem + 528 + 528;      // [8][128]
    float4* W2buf = smem + 528;           // [8][360] per K-chunk (aliases sE/Wbuf)
    int tid = threadIdx.x;
    int e0 = blockIdx.x * 16;
    const float4* e4 = (const float4*)e;
#pragma unroll
    for (int r = 0; r < 2; ++r) {
        int li = r * 256 + tid;
        int el = li >> 5, k4 = li & 31;
        sE[el * 33 + k4] = e4[(size_t)(e0 + el) * 32 + k4];
    }
    __syncthreads();
    int eg = tid >> 5, cg = tid & 31;
    int el0 = eg * 2;
    float acc[2][4] = {};
    gemm_tile<32>((const float4*)W1, sE, 33, Wbuf, el0, cg, acc, tid);
    float4 bb1 = ((const float4*)b1)[cg];
    sH[(el0 + 0) * 33 + cg] = make_float4(silu_f(acc[0][0] + bb1.x), silu_f(acc[0][1] + bb1.y),
                                          silu_f(acc[0][2] + bb1.z), silu_f(acc[0][3] + bb1.w));
    sH[(el0 + 1) * 33 + cg] = make_float4(silu_f(acc[1][0] + bb1.x), silu_f(acc[1][1] + bb1.y),
                                          silu_f(acc[1][2] + bb1.z), silu_f(acc[1][3] + bb1.w));
    __syncthreads();
    // 16 edges x 360 cols, K=128, K-chunked by 32 with W2 staged in LDS
    int els[6], c0s[6];
#pragma unroll
    for (int it = 0; it < 6; ++it) { int oi = it * 256 + tid; els[it] = oi / 90; c0s[it] = (oi % 90) * 4; }
    float acc2[6][4] = {};
    const float4* W2g = (const float4*)W2;
    for (int ch = 0; ch < 4; ++ch) {
        for (int li = tid; li < 2880; li += 256) {
            int kg = li / 360, c = li % 360;
            W2buf[li] = W2g[(size_t)c * 32 + ch * 8 + kg];
        }
        __syncthreads();
#pragma unroll
        for (int it = 0; it < 6; ++it) {
            if (it * 256 + tid < 1440) {
                int el = els[it], c0 = c0s[it];
#pragma unroll
                for (int kg = 0; kg < 8; ++kg) {
                    float4 a = sH[el * 33 + ch * 8 + kg];
#pragma unroll
                    for (int j = 0; j < 4; ++j) {
                        float4 w = W2buf[kg * 360 + c0 + j];
                        acc2[it][j] = fmaf(a.x, w.x, fmaf(a.y, w.y, fmaf(a.z, w.z, fmaf(a.w, w.w, acc2[it][j]))));
                    }
                }
            }
        }
        __syncthreads();
    }
#pragma unroll
    for (int it = 0; it < 6; ++it) {
        int oi = it * 256 + tid;
        if (oi < 1440) {
            int el = els[it], c0 = c0s[it];
            int ge = e0 + el;
            float r = res[(size_t)ge * MF + (c0 / 40)];   // 40 % 4 == 0: c0..c0+3 share f
            float4 bb = ((const float4*)b2)[c0 >> 2];
            float4 o;
            o.x = acc2[it][0] + bb.x + r;
            o.y = acc2[it][1] + bb.y + r;
            o.z = acc2[it][2] + bb.z + r;
            o.w = acc2[it][3] + bb.w + r;
            *((float4*)(out + (size_t)ge * 360 + c0)) = o;
        }
    }
}

extern "C" void kernel_launch(void* const* d_in, const int* in_sizes, int n_in,
                              void* d_out, int out_size, void* d_ws, size_t ws_size,
                              hipStream_t stream)
{
    const float* edge_attr  = (const float*)d_in[0];
    const int*   edge_type  = (const int*)d_in[1];
    const float* pos        = (const float*)d_in[2];
    const int*   pos_w      = (const int*)d_in[3];
    const int*   edge_index = (const int*)d_in[4];
    const float* layer_embed= (const float*)d_in[5];
    const float* wte        = (const float*)d_in[6];
    const float* node_W     = (const float*)d_in[7];
    const float* node_b     = (const float*)d_in[8];
    const float* edge_W     = (const float*)d_in[9];
    const float* edge_b     = (const float*)d_in[10];
    const float* gnn_We     = (const float*)d_in[11];
    const float* gnn_be     = (const float*)d_in[12];
    const float* gnn_Wpre   = (const float*)d_in[13];
    const float* gnn_bpre   = (const float*)d_in[14];
    const float* gnn_Wpost  = (const float*)d_in[15];
    const float* gnn_bpost  = (const float*)d_in[16];
    const float* out_W1     = (const float*)d_in[17];
    const float* out_b1     = (const float*)d_in[18];
    const float* out_W2     = (const float*)d_in[19];
    const float* out_b2     = (const float*)d_in[20];

    const int E = in_sizes[1];   // edge_type count = 400000 (div by 16)
    const int N = in_sizes[3];   // pos_w count = 50000 (div by 16)
    const int* src = edge_index;
    const int* dst = edge_index + E;

    // workspace carve (all f32): x | e | agg | deg | res  ~= 271 MB
    float* xbuf = (float*)d_ws;
    float* ebuf = xbuf + (size_t)N * HID;
    float* agg  = ebuf + (size_t)E * HID;
    float* deg  = agg + (size_t)N * HID;
    float* res  = deg + N;
    float* outx = (float*)d_out;                 // output 0: final x [N,128]
    float* oute = outx + (size_t)N * HID;        // output 1: [E,9,40]

    hipMemsetAsync(deg, 0, sizeof(float) * (size_t)N, stream);
    k_node_init<<<N, HID, 0, stream>>>(pos, pos_w, wte, node_W, node_b, xbuf);
    k_edge_init<<<E / 16, 256, 0, stream>>>(edge_attr, edge_type, layer_embed, edge_W, edge_b, ebuf, res);
    k_deg<<<(E + 255) / 256, 256, 0, stream>>>(dst, deg, E);

    for (int l = 0; l < LNUM; ++l) {
        hipMemsetAsync(agg, 0, sizeof(float) * (size_t)N * HID, stream);
        k_edge_msg<<<E / 16, 256, 0, stream>>>(xbuf, ebuf, src, dst,
            gnn_We + (size_t)l * HID * 3 * HID, gnn_be + (size_t)l * HID,
            gnn_Wpre + (size_t)l * HID * 3 * HID, gnn_bpre + (size_t)l * HID,
            agg);
        float* xo = (l == LNUM - 1) ? outx : xbuf;
        k_x_upd<<<N / 16, 256, 0, stream>>>(xbuf, agg, deg,
            gnn_Wpost + (size_t)l * HID * 2 * HID, gnn_bpost + (size_t)l * HID,
            xo, (l < LNUM - 1) ? 1 : 0);
    }
    k_readout<<<E / 16, 256, 0, stream>>>(ebuf, out_W1, out_b1, out_W2, out_b2, res, oute);
}

// Round 2
// 10378.696 us; speedup vs baseline: 1.3569x; 1.3569x over previous
//
#include <hip/hip_runtime.h>
#include <math.h>

#define MF 9
#define CTX 5
#define HID 128
#define LPE 8
#define LNUM 3

__device__ __forceinline__ float silu_f(float v) { return v / (1.0f + __expf(-v)); }

// ---------------- node init: x = wte[pos_w] + pos @ node_W^T + node_b ----------------
__global__ void k_node_init(const float* __restrict__ pos, const int* __restrict__ pos_w,
                            const float* __restrict__ wte, const float* __restrict__ nW,
                            const float* __restrict__ nb, float* __restrict__ x)
{
    int n = blockIdx.x;
    int t = threadIdx.x;
    __shared__ float sp[LPE];
    if (t < LPE) sp[t] = pos[(size_t)n * LPE + t];
    __syncthreads();
    float acc = nb[t];
    const float* w = nW + t * LPE;
#pragma unroll
    for (int j = 0; j < LPE; ++j) acc = fmaf(sp[j], w[j], acc);
    int pw = pos_w[n];
    x[(size_t)n * HID + t] = wte[(size_t)pw * HID + t] + acc;
}

// ---------------- edge init: e = layer_embed[type] + edge_attr @ edge_W^T + edge_b; res extract ----
__global__ __launch_bounds__(256)
void k_edge_init(const float* __restrict__ eattr, const int* __restrict__ etype,
                 const float* __restrict__ lemb, const float* __restrict__ eW,
                 const float* __restrict__ eb, float* __restrict__ e,
                 float* __restrict__ res)
{
    __shared__ float sW[HID][49];   // stride 49 floats: odd -> conflict-free column reads
    __shared__ float sR[16][49];
    int tid = threadIdx.x;
    int e0 = blockIdx.x * 16;
    for (int li = tid; li < HID * 45; li += 256) { int c = li / 45, k = li % 45; sW[c][k] = eW[li]; }
    for (int li = tid; li < 16 * 45; li += 256) { int el = li / 45, k = li % 45; sR[el][k] = eattr[(size_t)(e0 + el) * 45 + k]; }
    __syncthreads();
    if (tid < 16 * MF) { int el = tid / MF, f = tid % MF; res[(size_t)(e0 + el) * MF + f] = sR[el][f * CTX + (CTX - 1)]; }
    int eg = tid >> 5, cg = tid & 31;
    int el0 = eg * 2;
    float acc[2][4] = {};
    for (int k = 0; k < 45; ++k) {
        float a0 = sR[el0][k], a1 = sR[el0 + 1][k];
#pragma unroll
        for (int j = 0; j < 4; ++j) {
            float w = sW[cg + 32 * j][k];          // inter-lane stride 49 floats: conflict-free
            acc[0][j] = fmaf(a0, w, acc[0][j]);
            acc[1][j] = fmaf(a1, w, acc[1][j]);
        }
    }
#pragma unroll
    for (int i = 0; i < 2; ++i) {
        int ge = e0 + el0 + i;
        int ty = etype[ge];
#pragma unroll
        for (int j = 0; j < 4; ++j) {
            int c = cg + 32 * j;
            e[(size_t)ge * HID + c] = acc[i][j] + lemb[(size_t)ty * HID + c] + eb[c];
        }
    }
}

// ---------------- degree count ----------------
__global__ void k_deg(const int* __restrict__ dst, float* __restrict__ deg, int E)
{
    int i = blockIdx.x * 256 + threadIdx.x;
    if (i < E) atomicAdd(&deg[dst[i]], 1.0f);
}

// ---------------- generic 16-row x 128-col tile GEMM, K = K4*4, A in LDS ----------------
// Thread (eg,cg) owns rows el0..el0+1 and columns {cg, cg+32, cg+64, cg+96}.
// Wbuf read: inter-lane stride 1 float4 -> bank-conflict-free.
template <int K4>
__device__ __forceinline__ void gemm_tile(const float4* __restrict__ Wg, const float4* sA, int saStride,
                                          float4* Wbuf, int el0, int cg, float acc[2][4], int tid)
{
    for (int ch = 0; ch < K4 / 8; ++ch) {
#pragma unroll
        for (int r = 0; r < 4; ++r) {
            int li = r * 256 + tid;
            int kg = li >> 7, c = li & 127;
            Wbuf[kg * 128 + c] = Wg[(size_t)c * K4 + ch * 8 + kg];
        }
        __syncthreads();
#pragma unroll
        for (int kg = 0; kg < 8; ++kg) {
            float4 a0 = sA[(el0 + 0) * saStride + ch * 8 + kg];   // broadcast within 32-lane group
            float4 a1 = sA[(el0 + 1) * saStride + ch * 8 + kg];
#pragma unroll
            for (int j = 0; j < 4; ++j) {
                float4 w = Wbuf[kg * 128 + cg + 32 * j];
                acc[0][j] = fmaf(a0.x, w.x, fmaf(a0.y, w.y, fmaf(a0.z, w.z, fmaf(a0.w, w.w, acc[0][j]))));
                acc[1][j] = fmaf(a1.x, w.x, fmaf(a1.y, w.y, fmaf(a1.z, w.z, fmaf(a1.w, w.w, acc[1][j]))));
            }
        }
        __syncthreads();
    }
}

// ---------------- per-layer fused: e' = silu([xs|xd|e]@We^T+be); m = silu([xs|xd|e']@Wpre^T+bpre);
//                  agg[dst] += m  (e updated in place) ----------
__global__ __launch_bounds__(256)
void k_edge_msg(const float* __restrict__ x, float* __restrict__ e,
                const int* __restrict__ src, const int* __restrict__ dst,
                const float* __restrict__ We, const float* __restrict__ be,
                const float* __restrict__ Wpre, const float* __restrict__ bpre,
                float* __restrict__ agg)
{
    __shared__ float4 sA[16 * 97];    // [16 rows][96 f4 = 384 f32], padded stride 97
    __shared__ float4 Wbuf[1024];     // 32k x 128c chunk
    __shared__ int sS[16], sD[16];
    int tid = threadIdx.x;
    int e0 = blockIdx.x * 16;
    if (tid < 16) sS[tid] = src[e0 + tid];
    else if (tid < 32) sD[tid - 16] = dst[e0 + tid - 16];
    __syncthreads();
    const float4* x4 = (const float4*)x;
    const float4* e4 = (const float4*)e;
#pragma unroll
    for (int r = 0; r < 6; ++r) {
        int li = r * 256 + tid;       // 16 edges * 96 f4
        int el = li / 96, k4 = li % 96;
        float4 v;
        if (k4 < 32) v = x4[(size_t)sS[el] * 32 + k4];
        else if (k4 < 64) v = x4[(size_t)sD[el] * 32 + (k4 - 32)];
        else v = e4[(size_t)(e0 + el) * 32 + (k4 - 64)];
        sA[el * 97 + k4] = v;
    }
    __syncthreads();
    int eg = tid >> 5, cg = tid & 31;
    int el0 = eg * 2;
    float acc[2][4] = {};
    gemm_tile<96>((const float4*)We, sA, 97, Wbuf, el0, cg, acc, tid);
    float en[2][4];
#pragma unroll
    for (int i = 0; i < 2; ++i)
#pragma unroll
        for (int j = 0; j < 4; ++j)
            en[i][j] = silu_f(acc[i][j] + be[cg + 32 * j]);
    // gemm_tile ends with __syncthreads(): all reads of old e are complete
    float* sAf = (float*)sA;
#pragma unroll
    for (int i = 0; i < 2; ++i) {
        int el = el0 + i;
#pragma unroll
        for (int j = 0; j < 4; ++j) {
            int c = cg + 32 * j;
            sAf[(el * 97 + 64) * 4 + c] = en[i][j];
            e[(size_t)(e0 + el) * HID + c] = en[i][j];
        }
    }
    __syncthreads();
    float acc2[2][4] = {};
    gemm_tile<96>((const float4*)Wpre, sA, 97, Wbuf, el0, cg, acc2, tid);
#pragma unroll
    for (int i = 0; i < 2; ++i) {
        float* ap = agg + (size_t)sD[el0 + i] * HID;
#pragma unroll
        for (int j = 0; j < 4; ++j) {
            int c = cg + 32 * j;
            atomicAdd(ap + c, silu_f(acc2[i][j] + bpre[c]));
        }
    }
}

// ---------------- node update: x' = [x | agg/deg] @ Wpost^T + bpost (silu if not last) -------------
__global__ __launch_bounds__(256)
void k_x_upd(const float* __restrict__ x, const float* __restrict__ agg,
             const float* __restrict__ deg, const float* __restrict__ Wpost,
             const float* __restrict__ bpost, float* __restrict__ xout, int doSilu)
{
    __shared__ float4 sA[16 * 65];    // [16][64 f4 = 256 f32], stride 65
    __shared__ float4 Wbuf[1024];
    int tid = threadIdx.x;
    int n0 = blockIdx.x * 16;
    const float4* x4 = (const float4*)x;
    const float4* a4 = (const float4*)agg;
#pragma unroll
    for (int r = 0; r < 4; ++r) {
        int li = r * 256 + tid;
        int el = li >> 6, k4 = li & 63;
        int n = n0 + el;
        float4 v;
        if (k4 < 32) v = x4[(size_t)n * 32 + k4];
        else {
            float invd = 1.0f / fmaxf(deg[n], 1.0f);
            float4 a = a4[(size_t)n * 32 + (k4 - 32)];
            v = make_float4(a.x * invd, a.y * invd, a.z * invd, a.w * invd);
        }
        sA[el * 65 + k4] = v;
    }
    __syncthreads();
    int eg = tid >> 5, cg = tid & 31;
    int el0 = eg * 2;
    float acc[2][4] = {};
    gemm_tile<64>((const float4*)Wpost, sA, 65, Wbuf, el0, cg, acc, tid);
#pragma unroll
    for (int i = 0; i < 2; ++i) {
        int n = n0 + el0 + i;
#pragma unroll
        for (int j = 0; j < 4; ++j) {
            int c = cg + 32 * j;
            float o = acc[i][j] + bpost[c];
            if (doSilu) o = silu_f(o);
            xout[(size_t)n * HID + c] = o;
        }
    }
}

// ---------------- readout: h = silu(e@W1^T+b1); out = h@W2^T + b2 + res ----------------
__global__ __launch_bounds__(256)
void k_readout(const float* __restrict__ e, const float* __restrict__ W1,
               const float* __restrict__ b1, const float* __restrict__ W2,
               const float* __restrict__ b2, const float* __restrict__ res,
               float* __restrict__ out)
{
    __shared__ float4 smem[528 + 2880];   // 54.5 KB
    float4* sH = smem;                    // [16][33]
    float4* sE = smem + 528;              // [16][33] (dead after h-GEMM)
    float4* Wbuf = smem + 528 + 528;      // [8][128]
    float4* W2buf = smem + 528;           // [8][360] per K-chunk (aliases sE/Wbuf)
    int tid = threadIdx.x;
    int e0 = blockIdx.x * 16;
    const float4* e4 = (const float4*)e;
#pragma unroll
    for (int r = 0; r < 2; ++r) {
        int li = r * 256 + tid;
        int el = li >> 5, k4 = li & 31;
        sE[el * 33 + k4] = e4[(size_t)(e0 + el) * 32 + k4];
    }
    __syncthreads();
    int eg = tid >> 5, cg = tid & 31;
    int el0 = eg * 2;
    float acc[2][4] = {};
    gemm_tile<32>((const float4*)W1, sE, 33, Wbuf, el0, cg, acc, tid);
    float* sHf = (float*)sH;
#pragma unroll
    for (int i = 0; i < 2; ++i) {
        int el = el0 + i;
#pragma unroll
        for (int j = 0; j < 4; ++j) {
            int c = cg + 32 * j;
            sHf[el * 132 + c] = silu_f(acc[i][j] + b1[c]);   // sH stride 33 f4 = 132 floats
        }
    }
    __syncthreads();
    // 16 edges x 360 cols, K=128, K-chunked by 32 with W2 staged in LDS.
    // Thread owns columns {q, q+90, q+180, q+270}: inter-lane stride 1 f4 on W2buf reads.
    int els[6], q0s[6];
#pragma unroll
    for (int it = 0; it < 6; ++it) { int oi = it * 256 + tid; els[it] = oi / 90; q0s[it] = oi % 90; }
    float acc2[6][4] = {};
    const float4* W2g = (const float4*)W2;
    for (int ch = 0; ch < 4; ++ch) {
        for (int li = tid; li < 2880; li += 256) {
            int kg = li / 360, c = li % 360;
            W2buf[li] = W2g[(size_t)c * 32 + ch * 8 + kg];
        }
        __syncthreads();
#pragma unroll
        for (int it = 0; it < 6; ++it) {
            if (it * 256 + tid < 1440) {
                int el = els[it], q = q0s[it];
#pragma unroll
                for (int kg = 0; kg < 8; ++kg) {
                    float4 a = sH[el * 33 + ch * 8 + kg];
#pragma unroll
                    for (int j = 0; j < 4; ++j) {
                        float4 w = W2buf[kg * 360 + q + 90 * j];
                        acc2[it][j] = fmaf(a.x, w.x, fmaf(a.y, w.y, fmaf(a.z, w.z, fmaf(a.w, w.w, acc2[it][j]))));
                    }
                }
            }
        }
        __syncthreads();
    }
#pragma unroll
    for (int it = 0; it < 6; ++it) {
        int oi = it * 256 + tid;
        if (oi < 1440) {
            int el = els[it], q = q0s[it];
            int ge = e0 + el;
#pragma unroll
            for (int j = 0; j < 4; ++j) {
                int c = q + 90 * j;
                float r = res[(size_t)ge * MF + (c / 40)];
                out[(size_t)ge * 360 + c] = acc2[it][j] + b2[c] + r;
            }
        }
    }
}

extern "C" void kernel_launch(void* const* d_in, const int* in_sizes, int n_in,
                              void* d_out, int out_size, void* d_ws, size_t ws_size,
                              hipStream_t stream)
{
    const float* edge_attr  = (const float*)d_in[0];
    const int*   edge_type  = (const int*)d_in[1];
    const float* pos        = (const float*)d_in[2];
    const int*   pos_w      = (const int*)d_in[3];
    const int*   edge_index = (const int*)d_in[4];
    const float* layer_embed= (const float*)d_in[5];
    const float* wte        = (const float*)d_in[6];
    const float* node_W     = (const float*)d_in[7];
    const float* node_b     = (const float*)d_in[8];
    const float* edge_W     = (const float*)d_in[9];
    const float* edge_b     = (const float*)d_in[10];
    const float* gnn_We     = (const float*)d_in[11];
    const float* gnn_be     = (const float*)d_in[12];
    const float* gnn_Wpre   = (const float*)d_in[13];
    const float* gnn_bpre   = (const float*)d_in[14];
    const float* gnn_Wpost  = (const float*)d_in[15];
    const float* gnn_bpost  = (const float*)d_in[16];
    const float* out_W1     = (const float*)d_in[17];
    const float* out_b1     = (const float*)d_in[18];
    const float* out_W2     = (const float*)d_in[19];
    const float* out_b2     = (const float*)d_in[20];

    const int E = in_sizes[1];   // 400000 (divisible by 16)
    const int N = in_sizes[3];   // 50000 (divisible by 16)
    const int* src = edge_index;
    const int* dst = edge_index + E;

    // workspace carve (all f32): x | e | agg | deg | res
    float* xbuf = (float*)d_ws;
    float* ebuf = xbuf + (size_t)N * HID;
    float* agg  = ebuf + (size_t)E * HID;
    float* deg  = agg + (size_t)N * HID;
    float* res  = deg + N;
    float* outx = (float*)d_out;                 // output 0: final x [N,128]
    float* oute = outx + (size_t)N * HID;        // output 1: [E,9,40]

    hipMemsetAsync(deg, 0, sizeof(float) * (size_t)N, stream);
    k_node_init<<<N, HID, 0, stream>>>(pos, pos_w, wte, node_W, node_b, xbuf);
    k_edge_init<<<E / 16, 256, 0, stream>>>(edge_attr, edge_type, layer_embed, edge_W, edge_b, ebuf, res);
    k_deg<<<(E + 255) / 256, 256, 0, stream>>>(dst, deg, E);

    for (int l = 0; l < LNUM; ++l) {
        hipMemsetAsync(agg, 0, sizeof(float) * (size_t)N * HID, stream);
        k_edge_msg<<<E / 16, 256, 0, stream>>>(xbuf, ebuf, src, dst,
            gnn_We + (size_t)l * HID * 3 * HID, gnn_be + (size_t)l * HID,
            gnn_Wpre + (size_t)l * HID * 3 * HID, gnn_bpre + (size_t)l * HID,
            agg);
        float* xo = (l == LNUM - 1) ? outx : xbuf;
        k_x_upd<<<N / 16, 256, 0, stream>>>(xbuf, agg, deg,
            gnn_Wpost + (size_t)l * HID * 2 * HID, gnn_bpost + (size_t)l * HID,
            xo, (l < LNUM - 1) ? 1 : 0);
    }
    k_readout<<<E / 16, 256, 0, stream>>>(ebuf, out_W1, out_b1, out_W2, out_b2, res, oute);
}